// Round 5
// baseline (109.170 us; speedup 1.0000x reference)
//
#include <hip/hip_runtime.h>
#include <hip/hip_bf16.h>

// BEVFormerLite fused: project BEV grid into 6 cameras, bilinear-sample,
// average valid cams, 1x1 conv + BN + ReLU.
// B=4 N=6 C=256 fH=29 fW=50, BEV 200x200 (P=40000). Output (4,256,200,200) f32.
//
// Round 5: occupancy-first restructure of the fused kernel.
//  k0 prep+transpose (merged, unchanged from r4).
//  k1 fused: 256-thread / 4-wave blocks, 32 points each (grid 1250 x 4).
//     phase A: projection -> compacted 8B slots (LDS).
//     phase B: gather-sample in TWO 16-channel passes (acc[16] keeps VGPR low).
//     phase C: K=256 MFMA GEMM, per-wave 64o x 32p, A direct from L2-resident W.
//     LDS ~19KB, target 85 VGPR -> 6 blocks (24 waves) per CU for phase overlap.

#define P_TOT  40000
#define FH     29
#define FW     50
#define NCAM   6

typedef short bf16x8 __attribute__((ext_vector_type(8)));
typedef float f32x4  __attribute__((ext_vector_type(4)));
typedef unsigned short u16x8 __attribute__((ext_vector_type(8)));

__device__ __forceinline__ float bf2f(unsigned short u) {
    union { unsigned int i; float f; } x; x.i = ((unsigned int)u) << 16; return x.f;
}
__device__ __forceinline__ unsigned short f2bf(float f) {
    union { float f; unsigned int i; } x; x.f = f;
    unsigned int i = x.i;
    return (unsigned short)((i + 0x7FFFu + ((i >> 16) & 1u)) >> 16);  // RNE
}

// ---------------- k0: transpose + W->bf16 + geometry + BN fold ----------------
__global__ __launch_bounds__(256) void prep_transpose_kernel(
        const float* __restrict__ feats, const float* __restrict__ K,
        const float* __restrict__ E, const float* __restrict__ convw,
        const float* __restrict__ convb, const float* __restrict__ gamma,
        const float* __restrict__ beta, const float* __restrict__ mean,
        const float* __restrict__ var, float* __restrict__ params,
        float* __restrict__ sb, unsigned short* __restrict__ wbf,
        unsigned short* __restrict__ ft) {
    __shared__ unsigned short tile[256][58];   // pad 50->58 (116B stride)
    int blk = blockIdx.x;
    int t   = threadIdx.x;
    if (blk < 256) {                           // W -> bf16 (65536 entries)
        int idx = blk * 256 + t;
        wbf[idx] = f2bf(convw[idx]);
    }
    if (blk == 696) {                          // geometry + BN fold
        int o = t;
        float rstd = rsqrtf(var[o] + 1e-5f);
        float s = gamma[o] * rstd;
        sb[o]       = s;
        sb[256 + o] = (convb[o] - mean[o]) * s + beta[o];
        if (o >= 24) return;
        const float* e = E + o * 16;
        const float* k = K + o * 9;
        float a00=e[0], a01=e[1], a02=e[2],  t0=e[3];
        float a10=e[4], a11=e[5], a12=e[6],  t1=e[7];
        float a20=e[8], a21=e[9], a22=e[10], t2=e[11];
        float c00 =  (a11*a22 - a12*a21);
        float c01 = -(a10*a22 - a12*a20);
        float c02 =  (a10*a21 - a11*a20);
        float det = a00*c00 + a01*c01 + a02*c02;
        float id = 1.0f / det;
        float i00 =  c00*id;
        float i01 = -(a01*a22 - a02*a21)*id;
        float i02 =  (a01*a12 - a02*a11)*id;
        float i10 =  c01*id;
        float i11 =  (a00*a22 - a02*a20)*id;
        float i12 = -(a00*a12 - a02*a10)*id;
        float i20 =  c02*id;
        float i21 = -(a00*a21 - a01*a20)*id;
        float i22 =  (a00*a11 - a01*a10)*id;
        float tp0 = -(i00*t0 + i01*t1 + i02*t2);
        float tp1 = -(i10*t0 + i11*t1 + i12*t2);
        float tp2 = -(i20*t0 + i21*t1 + i22*t2);
        float* q = params + o * 12;
        q[0] = k[0]*i00 + k[1]*i10 + k[2]*i20;
        q[1] = k[0]*i01 + k[1]*i11 + k[2]*i21;
        q[2] = k[0]*tp0 + k[1]*tp1 + k[2]*tp2;
        q[3] = k[3]*i00 + k[4]*i10 + k[5]*i20;
        q[4] = k[3]*i01 + k[4]*i11 + k[5]*i21;
        q[5] = k[3]*tp0 + k[4]*tp1 + k[5]*tp2;
        q[6] = k[6]*i00 + k[7]*i10 + k[8]*i20;
        q[7] = k[6]*i01 + k[7]*i11 + k[8]*i21;
        q[8] = k[6]*tp0 + k[7]*tp1 + k[8]*tp2;
        q[9]  = i20;
        q[10] = i21;
        q[11] = tp2;
        return;
    }
    // transpose one (bn,y) row: feats (bn,c,y,x) f32 -> ft (bn,y,x,c) bf16
    int bn = blk / FH, y = blk - bn * FH;
    const float* src = feats + (size_t)bn * 256 * FH * FW + y * FW;
    #pragma unroll
    for (int i = 0; i < 50; ++i) {             // reads: runs of 50 consecutive floats
        int flat = i * 256 + t;
        int c = flat / 50;
        int x = flat - c * 50;
        tile[c][x] = f2bf(src[c * FH * FW + x]);
    }
    __syncthreads();
    unsigned short* dst = ft + (size_t)blk * 50 * 256;
    #pragma unroll
    for (int i = 0; i < 25; ++i) {             // writes: fully coalesced u32
        int flat = i * 512 + t * 2;
        int x = flat >> 8;
        int c = flat & 255;
        unsigned int v = (unsigned int)tile[c][x] | ((unsigned int)tile[c + 1][x] << 16);
        *(unsigned int*)(dst + x * 256 + c) = v;
    }
}

// ---------------- k1: fused sample + GEMM + BN + ReLU (32 pts / 4 waves) ----------------
__global__ __launch_bounds__(256, 6) void fused_kernel(const unsigned short* __restrict__ ft,
                                                       const float* __restrict__ params,
                                                       const unsigned short* __restrict__ wbf,
                                                       const float* __restrict__ sb,
                                                       float* __restrict__ out) {
    __shared__ unsigned short Bt[32][264];        // bev tile [p][c], 528B rows
    __shared__ int           sbf[32][6];          // slot: base|okx|oky, -1 = invalid
    __shared__ unsigned int  swxy[32][6];         // wx,wy as u16 fixed-point
    __shared__ int           scnt[32];
    __shared__ float         sscale[32];
    __shared__ float         ssb[512];            // scale[256] + bias[256]

    int tid   = threadIdx.x;
    int pbase = blockIdx.x * 32;
    int b     = blockIdx.y;

    ssb[tid]       = sb[tid];
    ssb[tid + 256] = sb[tid + 256];

    // ---- phase A: projection, one thread per (point, cam) ----
    if (tid < 192) {
        int pt  = tid / 6;
        int cam = tid - pt * 6;
        int p   = pbase + pt;
        float gx = -49.75f + 0.5f * (float)(p % 200);
        float gy = -49.75f + 0.5f * (float)(p / 200);
        const float* q = params + (b * NCAM + cam) * 12;
        float wh    = q[6] * gx + q[7]  * gy + q[8];
        float depth = q[9] * gx + q[10] * gy + q[11];
        float inv = 1.0f / (wh + 1e-6f);
        float u = (q[0] * gx + q[1] * gy + q[2]) * inv;
        float v = (q[3] * gx + q[4] * gy + q[5]) * inv;
        float un = u * (50.0f / 1600.0f) * (2.0f / 49.0f) - 1.0f;
        float vn = v * (29.0f / 928.0f)  * (2.0f / 28.0f) - 1.0f;
        int bf = -1; unsigned int wxy = 0;
        if (depth > 0.1f && un >= -1.0f && un <= 1.0f &&
                            vn >= -1.0f && vn <= 1.0f) {
            float xs = (un + 1.0f) * 0.5f * 49.0f;
            float ys = (vn + 1.0f) * 0.5f * 28.0f;
            float x0f = floorf(xs), y0f = floorf(ys);
            float wx = xs - x0f, wy = ys - y0f;
            int x0 = (int)x0f, y0 = (int)y0f;
            int okx = (x0 < FW - 1) ? 1 : 0;
            int oky = (y0 < FH - 1) ? 2 : 0;
            int base = (((b * NCAM + cam) * FH + y0) * FW + x0) * 256; // low 8 bits free
            bf  = base | okx | oky;
            wxy = (unsigned int)(wx * 65535.0f + 0.5f)
                | ((unsigned int)(wy * 65535.0f + 0.5f) << 16);
        }
        sbf[pt][cam]  = bf;
        swxy[pt][cam] = wxy;
    }
    __syncthreads();

    // ---- compact slots per point (cam order preserved) ----
    if (tid < 32) {
        int c = 0;
        #pragma unroll
        for (int cam = 0; cam < NCAM; ++cam) {
            int v = sbf[tid][cam];
            unsigned int w = swxy[tid][cam];
            if (v >= 0) { sbf[tid][c] = v; swxy[tid][c] = w; ++c; }
        }
        scnt[tid]   = c;
        sscale[tid] = 1.0f / ((float)c + 1e-6f);
    }
    __syncthreads();

    // ---- phase B: sample, 8 threads/point x 32 ch, two 16-ch passes ----
    {
        int pt = tid >> 3, sub = tid & 7;
        int n = scnt[pt];
        float sc = sscale[pt];
        #pragma unroll
        for (int pass = 0; pass < 2; ++pass) {
            int ch0 = sub * 32 + pass * 16;
            float acc[16];
            #pragma unroll
            for (int j = 0; j < 16; ++j) acc[j] = 0.0f;
            for (int s = 0; s < n; ++s) {
                int bf = sbf[pt][s];
                unsigned int wxy = swxy[pt][s];
                int base = bf & ~255;
                int okx = bf & 1, oky = bf & 2;
                float wx = (float)(wxy & 0xffffu) * (1.0f / 65535.0f);
                float wy = (float)(wxy >> 16)     * (1.0f / 65535.0f);
                float iwx = 1.0f - wx, iwy = 1.0f - wy;
                float w00 = iwx * iwy;
                float w01 = okx ? wx * iwy : 0.0f;
                float w10 = oky ? iwx * wy : 0.0f;
                float w11 = (okx && oky) ? wx * wy : 0.0f;
                const unsigned short* p00 = ft + base + ch0;
                int o01 = okx ? 256 : 0;
                int o10 = oky ? FW * 256 : 0;
                #pragma unroll
                for (int qv = 0; qv < 2; ++qv) {
                    u16x8 v0 = *(const u16x8*)(p00 + qv * 8);
                    #pragma unroll
                    for (int j = 0; j < 8; ++j) acc[qv * 8 + j] += w00 * bf2f(v0[j]);
                }
                #pragma unroll
                for (int qv = 0; qv < 2; ++qv) {
                    u16x8 v1 = *(const u16x8*)(p00 + o01 + qv * 8);
                    #pragma unroll
                    for (int j = 0; j < 8; ++j) acc[qv * 8 + j] += w01 * bf2f(v1[j]);
                }
                #pragma unroll
                for (int qv = 0; qv < 2; ++qv) {
                    u16x8 v2 = *(const u16x8*)(p00 + o10 + qv * 8);
                    #pragma unroll
                    for (int j = 0; j < 8; ++j) acc[qv * 8 + j] += w10 * bf2f(v2[j]);
                }
                #pragma unroll
                for (int qv = 0; qv < 2; ++qv) {
                    u16x8 v3 = *(const u16x8*)(p00 + o10 + o01 + qv * 8);
                    #pragma unroll
                    for (int j = 0; j < 8; ++j) acc[qv * 8 + j] += w11 * bf2f(v3[j]);
                }
            }
            #pragma unroll
            for (int qv = 0; qv < 2; ++qv) {
                u16x8 ov;
                #pragma unroll
                for (int j = 0; j < 8; ++j) ov[j] = f2bf(acc[qv * 8 + j] * sc);
                *(u16x8*)&Bt[pt][ch0 + qv * 8] = ov;
            }
        }
    }
    __syncthreads();

    // ---- phase C: GEMM, 4 waves x (64o x 32p), K=256, A direct from global ----
    int lane = tid & 63, wv = tid >> 6;
    f32x4 acc2[4][2];
    #pragma unroll
    for (int f = 0; f < 4; ++f)
        #pragma unroll
        for (int nf = 0; nf < 2; ++nf) acc2[f][nf] = (f32x4){0.f, 0.f, 0.f, 0.f};
    int arow = wv * 64 + (lane & 15);
    int kq   = (lane >> 4) * 8;
    const unsigned short* wptr = wbf + arow * 256 + kq;   // W is L2-resident (128KB)
    #pragma unroll
    for (int kt = 0; kt < 8; ++kt) {
        bf16x8 a0 = *(const bf16x8*)(wptr + kt * 32);
        bf16x8 a1 = *(const bf16x8*)(wptr + 16 * 256 + kt * 32);
        bf16x8 a2 = *(const bf16x8*)(wptr + 32 * 256 + kt * 32);
        bf16x8 a3 = *(const bf16x8*)(wptr + 48 * 256 + kt * 32);
        #pragma unroll
        for (int nf = 0; nf < 2; ++nf) {
            bf16x8 bb = *(const bf16x8*)&Bt[nf * 16 + (lane & 15)][kt * 32 + kq];
            acc2[0][nf] = __builtin_amdgcn_mfma_f32_16x16x32_bf16(a0, bb, acc2[0][nf], 0, 0, 0);
            acc2[1][nf] = __builtin_amdgcn_mfma_f32_16x16x32_bf16(a1, bb, acc2[1][nf], 0, 0, 0);
            acc2[2][nf] = __builtin_amdgcn_mfma_f32_16x16x32_bf16(a2, bb, acc2[2][nf], 0, 0, 0);
            acc2[3][nf] = __builtin_amdgcn_mfma_f32_16x16x32_bf16(a3, bb, acc2[3][nf], 0, 0, 0);
        }
    }
    // ---- epilogue: BN + ReLU + store ----
    #pragma unroll
    for (int f = 0; f < 4; ++f) {
        #pragma unroll
        for (int nf = 0; nf < 2; ++nf) {
            #pragma unroll
            for (int r = 0; r < 4; ++r) {
                int o = wv * 64 + f * 16 + (lane >> 4) * 4 + r;
                float y = acc2[f][nf][r] * ssb[o] + ssb[256 + o];
                out[((size_t)(b * 256 + o)) * P_TOT + pbase + nf * 16 + (lane & 15)]
                    = fmaxf(y, 0.0f);
            }
        }
    }
}

extern "C" void kernel_launch(void* const* d_in, const int* in_sizes, int n_in,
                              void* d_out, int out_size, void* d_ws, size_t ws_size,
                              hipStream_t stream) {
    const float* feats = (const float*)d_in[0];
    const float* intr  = (const float*)d_in[1];
    const float* extr  = (const float*)d_in[2];
    const float* convw = (const float*)d_in[3];
    const float* convb = (const float*)d_in[4];
    const float* gamma = (const float*)d_in[5];
    const float* beta  = (const float*)d_in[6];
    const float* mean  = (const float*)d_in[7];
    const float* var   = (const float*)d_in[8];

    char* ws = (char*)d_ws;
    float*          params = (float*)(ws + 0);              // 1152 B
    float*          sb     = (float*)(ws + 2048);           // 2 KB
    unsigned short* wbf    = (unsigned short*)(ws + 4096);  // 128 KB
    unsigned short* ft     = (unsigned short*)(ws + 135168);// 17.0 MB
    float* out = (float*)d_out;

    hipLaunchKernelGGL(prep_transpose_kernel, dim3(697), dim3(256), 0, stream,
                       feats, intr, extr, convw, convb, gamma, beta, mean, var,
                       params, sb, wbf, ft);
    hipLaunchKernelGGL(fused_kernel, dim3(1250, 4), dim3(256), 0, stream,
                       ft, params, wbf, sb, out);
}

// Round 6
// 79.289 us; speedup vs baseline: 1.3769x; 1.3769x over previous
//
#include <hip/hip_runtime.h>
#include <hip/hip_bf16.h>

// BEVFormerLite fused: project BEV grid into 6 cameras, bilinear-sample,
// average valid cams, 1x1 conv + BN + ReLU.
// B=4 N=6 C=256 fH=29 fW=50, BEV 200x200 (P=40000). Output (4,256,200,200) f32.
//
// Round 6 = round 3 structure (best: 77us) + barrier-free phase C.
//  k0 prep+transpose (merged).
//  k1 fused: 512-thread / 8-wave blocks, 64 points (grid 625 x 4).
//     phase A: projection -> compacted 8B slots (LDS).
//     phase B: gather-sample 64 pts x 256 ch, acc[32]/thread (needs ~128 VGPR
//              for a deep in-flight load window -- do NOT cap occupancy; r4/r5
//              showed VGPR caps collapse gather ILP and go latency-bound).
//     phase C: K=256 MFMA GEMM; A-fragments DIRECT from L2-resident W (128KB);
//              zero barriers in the k-loop (vs r3's 8 syncthreads + 40KB Wt).
//     LDS ~37KB, launch_bounds(512,4) -> 128 VGPR, 2 blocks/CU.

#define P_TOT  40000
#define FH     29
#define FW     50
#define NCAM   6

typedef short bf16x8 __attribute__((ext_vector_type(8)));
typedef float f32x4  __attribute__((ext_vector_type(4)));
typedef unsigned short u16x8 __attribute__((ext_vector_type(8)));

__device__ __forceinline__ float bf2f(unsigned short u) {
    union { unsigned int i; float f; } x; x.i = ((unsigned int)u) << 16; return x.f;
}
__device__ __forceinline__ unsigned short f2bf(float f) {
    union { float f; unsigned int i; } x; x.f = f;
    unsigned int i = x.i;
    return (unsigned short)((i + 0x7FFFu + ((i >> 16) & 1u)) >> 16);  // RNE
}

// ---------------- k0: transpose + W->bf16 + geometry + BN fold ----------------
__global__ __launch_bounds__(256) void prep_transpose_kernel(
        const float* __restrict__ feats, const float* __restrict__ K,
        const float* __restrict__ E, const float* __restrict__ convw,
        const float* __restrict__ convb, const float* __restrict__ gamma,
        const float* __restrict__ beta, const float* __restrict__ mean,
        const float* __restrict__ var, float* __restrict__ params,
        float* __restrict__ sb, unsigned short* __restrict__ wbf,
        unsigned short* __restrict__ ft) {
    __shared__ unsigned short tile[256][58];   // pad 50->58 (116B stride)
    int blk = blockIdx.x;
    int t   = threadIdx.x;
    if (blk < 256) {                           // W -> bf16 (65536 entries)
        int idx = blk * 256 + t;
        wbf[idx] = f2bf(convw[idx]);
    }
    if (blk == 696) {                          // geometry + BN fold
        int o = t;
        float rstd = rsqrtf(var[o] + 1e-5f);
        float s = gamma[o] * rstd;
        sb[o]       = s;
        sb[256 + o] = (convb[o] - mean[o]) * s + beta[o];
        if (o >= 24) return;
        const float* e = E + o * 16;
        const float* k = K + o * 9;
        float a00=e[0], a01=e[1], a02=e[2],  t0=e[3];
        float a10=e[4], a11=e[5], a12=e[6],  t1=e[7];
        float a20=e[8], a21=e[9], a22=e[10], t2=e[11];
        float c00 =  (a11*a22 - a12*a21);
        float c01 = -(a10*a22 - a12*a20);
        float c02 =  (a10*a21 - a11*a20);
        float det = a00*c00 + a01*c01 + a02*c02;
        float id = 1.0f / det;
        float i00 =  c00*id;
        float i01 = -(a01*a22 - a02*a21)*id;
        float i02 =  (a01*a12 - a02*a11)*id;
        float i10 =  c01*id;
        float i11 =  (a00*a22 - a02*a20)*id;
        float i12 = -(a00*a12 - a02*a10)*id;
        float i20 =  c02*id;
        float i21 = -(a00*a21 - a01*a20)*id;
        float i22 =  (a00*a11 - a01*a10)*id;
        float tp0 = -(i00*t0 + i01*t1 + i02*t2);
        float tp1 = -(i10*t0 + i11*t1 + i12*t2);
        float tp2 = -(i20*t0 + i21*t1 + i22*t2);
        float* q = params + o * 12;
        q[0] = k[0]*i00 + k[1]*i10 + k[2]*i20;
        q[1] = k[0]*i01 + k[1]*i11 + k[2]*i21;
        q[2] = k[0]*tp0 + k[1]*tp1 + k[2]*tp2;
        q[3] = k[3]*i00 + k[4]*i10 + k[5]*i20;
        q[4] = k[3]*i01 + k[4]*i11 + k[5]*i21;
        q[5] = k[3]*tp0 + k[4]*tp1 + k[5]*tp2;
        q[6] = k[6]*i00 + k[7]*i10 + k[8]*i20;
        q[7] = k[6]*i01 + k[7]*i11 + k[8]*i21;
        q[8] = k[6]*tp0 + k[7]*tp1 + k[8]*tp2;
        q[9]  = i20;
        q[10] = i21;
        q[11] = tp2;
        return;
    }
    // transpose one (bn,y) row: feats (bn,c,y,x) f32 -> ft (bn,y,x,c) bf16
    int bn = blk / FH, y = blk - bn * FH;
    const float* src = feats + (size_t)bn * 256 * FH * FW + y * FW;
    #pragma unroll
    for (int i = 0; i < 50; ++i) {             // reads: runs of 50 consecutive floats
        int flat = i * 256 + t;
        int c = flat / 50;
        int x = flat - c * 50;
        tile[c][x] = f2bf(src[c * FH * FW + x]);
    }
    __syncthreads();
    unsigned short* dst = ft + (size_t)blk * 50 * 256;
    #pragma unroll
    for (int i = 0; i < 25; ++i) {             // writes: fully coalesced u32
        int flat = i * 512 + t * 2;
        int x = flat >> 8;
        int c = flat & 255;
        unsigned int v = (unsigned int)tile[c][x] | ((unsigned int)tile[c + 1][x] << 16);
        *(unsigned int*)(dst + x * 256 + c) = v;
    }
}

// ---------------- k1: fused sample + GEMM + BN + ReLU ----------------
__global__ __launch_bounds__(512, 4) void fused_kernel(const unsigned short* __restrict__ ft,
                                                       const float* __restrict__ params,
                                                       const unsigned short* __restrict__ wbf,
                                                       const float* __restrict__ sb,
                                                       float* __restrict__ out) {
    __shared__ unsigned short Bt[64][264];        // bev tile [p][c], 528B rows
    __shared__ int           sbf[64][6];          // slot: base|okx|oky, -1 = invalid
    __shared__ unsigned int  swxy[64][6];         // wx,wy as u16 fixed-point
    __shared__ int           scnt[64];
    __shared__ float         sscale[64];
    __shared__ float         ssb[512];            // scale[256] + bias[256]

    int tid   = threadIdx.x;
    int pbase = blockIdx.x * 64;
    int b     = blockIdx.y;

    ssb[tid] = sb[tid];

    // ---- phase A: projection, one thread per (point, cam) ----
    if (tid < 384) {
        int pt  = tid / 6;
        int cam = tid - pt * 6;
        int p   = pbase + pt;
        float gx = -49.75f + 0.5f * (float)(p % 200);
        float gy = -49.75f + 0.5f * (float)(p / 200);
        const float* q = params + (b * NCAM + cam) * 12;
        float wh    = q[6] * gx + q[7]  * gy + q[8];
        float depth = q[9] * gx + q[10] * gy + q[11];
        float inv = 1.0f / (wh + 1e-6f);
        float u = (q[0] * gx + q[1] * gy + q[2]) * inv;
        float v = (q[3] * gx + q[4] * gy + q[5]) * inv;
        float un = u * (50.0f / 1600.0f) * (2.0f / 49.0f) - 1.0f;
        float vn = v * (29.0f / 928.0f)  * (2.0f / 28.0f) - 1.0f;
        int bf = -1; unsigned int wxy = 0;
        if (depth > 0.1f && un >= -1.0f && un <= 1.0f &&
                            vn >= -1.0f && vn <= 1.0f) {
            float xs = (un + 1.0f) * 0.5f * 49.0f;
            float ys = (vn + 1.0f) * 0.5f * 28.0f;
            float x0f = floorf(xs), y0f = floorf(ys);
            float wx = xs - x0f, wy = ys - y0f;
            int x0 = (int)x0f, y0 = (int)y0f;
            int okx = (x0 < FW - 1) ? 1 : 0;
            int oky = (y0 < FH - 1) ? 2 : 0;
            int base = (((b * NCAM + cam) * FH + y0) * FW + x0) * 256; // low 8 bits free
            bf  = base | okx | oky;
            wxy = (unsigned int)(wx * 65535.0f + 0.5f)
                | ((unsigned int)(wy * 65535.0f + 0.5f) << 16);
        }
        sbf[pt][cam]  = bf;
        swxy[pt][cam] = wxy;
    }
    __syncthreads();

    // ---- compact slots per point (cam order preserved) ----
    if (tid < 64) {
        int c = 0;
        #pragma unroll
        for (int cam = 0; cam < NCAM; ++cam) {
            int v = sbf[tid][cam];
            unsigned int w = swxy[tid][cam];
            if (v >= 0) { sbf[tid][c] = v; swxy[tid][c] = w; ++c; }
        }
        scnt[tid]   = c;
        sscale[tid] = 1.0f / ((float)c + 1e-6f);
    }
    __syncthreads();

    // ---- phase B: sample, 8 threads/point x 32 channels ----
    {
        int pt = tid >> 3, sub = tid & 7, ch0 = sub * 32;
        float acc[32];
        #pragma unroll
        for (int j = 0; j < 32; ++j) acc[j] = 0.0f;
        int n = scnt[pt];
        for (int s = 0; s < n; ++s) {
            int bf = sbf[pt][s];
            unsigned int wxy = swxy[pt][s];
            int base = bf & ~255;
            int okx = bf & 1, oky = bf & 2;
            float wx = (float)(wxy & 0xffffu) * (1.0f / 65535.0f);
            float wy = (float)(wxy >> 16)     * (1.0f / 65535.0f);
            float iwx = 1.0f - wx, iwy = 1.0f - wy;
            float w00 = iwx * iwy;
            float w01 = okx ? wx * iwy : 0.0f;
            float w10 = oky ? iwx * wy : 0.0f;
            float w11 = (okx && oky) ? wx * wy : 0.0f;
            const unsigned short* p00 = ft + base + ch0;
            int o01 = okx ? 256 : 0;
            int o10 = oky ? FW * 256 : 0;
            #pragma unroll
            for (int qv = 0; qv < 4; ++qv) {
                u16x8 v0 = *(const u16x8*)(p00 + qv * 8);
                #pragma unroll
                for (int j = 0; j < 8; ++j) acc[qv * 8 + j] += w00 * bf2f(v0[j]);
            }
            #pragma unroll
            for (int qv = 0; qv < 4; ++qv) {
                u16x8 v1 = *(const u16x8*)(p00 + o01 + qv * 8);
                #pragma unroll
                for (int j = 0; j < 8; ++j) acc[qv * 8 + j] += w01 * bf2f(v1[j]);
            }
            #pragma unroll
            for (int qv = 0; qv < 4; ++qv) {
                u16x8 v2 = *(const u16x8*)(p00 + o10 + qv * 8);
                #pragma unroll
                for (int j = 0; j < 8; ++j) acc[qv * 8 + j] += w10 * bf2f(v2[j]);
            }
            #pragma unroll
            for (int qv = 0; qv < 4; ++qv) {
                u16x8 v3 = *(const u16x8*)(p00 + o10 + o01 + qv * 8);
                #pragma unroll
                for (int j = 0; j < 8; ++j) acc[qv * 8 + j] += w11 * bf2f(v3[j]);
            }
        }
        float sc = sscale[pt];
        #pragma unroll
        for (int qv = 0; qv < 4; ++qv) {
            u16x8 ov;
            #pragma unroll
            for (int j = 0; j < 8; ++j) ov[j] = f2bf(acc[qv * 8 + j] * sc);
            *(u16x8*)&Bt[pt][ch0 + qv * 8] = ov;
        }
    }
    __syncthreads();

    // ---- phase C: GEMM, 8 waves x (32o x 64p), K=256, A direct from L2, no barriers ----
    int lane = tid & 63, wv = tid >> 6;
    f32x4 acc2[2][4];
    #pragma unroll
    for (int f = 0; f < 2; ++f)
        #pragma unroll
        for (int nf = 0; nf < 4; ++nf) acc2[f][nf] = (f32x4){0.f, 0.f, 0.f, 0.f};
    int arow = wv * 32 + (lane & 15);
    int kq   = (lane >> 4) * 8;
    const unsigned short* wptr = wbf + arow * 256 + kq;   // W is L2-resident (128KB)
    #pragma unroll
    for (int kt = 0; kt < 8; ++kt) {
        bf16x8 a0 = *(const bf16x8*)(wptr + kt * 32);
        bf16x8 a1 = *(const bf16x8*)(wptr + 16 * 256 + kt * 32);
        #pragma unroll
        for (int nf = 0; nf < 4; ++nf) {
            bf16x8 bb = *(const bf16x8*)&Bt[nf * 16 + (lane & 15)][kt * 32 + kq];
            acc2[0][nf] = __builtin_amdgcn_mfma_f32_16x16x32_bf16(a0, bb, acc2[0][nf], 0, 0, 0);
            acc2[1][nf] = __builtin_amdgcn_mfma_f32_16x16x32_bf16(a1, bb, acc2[1][nf], 0, 0, 0);
        }
    }
    // ---- epilogue: BN + ReLU + store ----
    #pragma unroll
    for (int f = 0; f < 2; ++f) {
        #pragma unroll
        for (int nf = 0; nf < 4; ++nf) {
            #pragma unroll
            for (int r = 0; r < 4; ++r) {
                int o = wv * 32 + f * 16 + (lane >> 4) * 4 + r;
                float y = acc2[f][nf][r] * ssb[o] + ssb[256 + o];
                out[((size_t)(b * 256 + o)) * P_TOT + pbase + nf * 16 + (lane & 15)]
                    = fmaxf(y, 0.0f);
            }
        }
    }
}

extern "C" void kernel_launch(void* const* d_in, const int* in_sizes, int n_in,
                              void* d_out, int out_size, void* d_ws, size_t ws_size,
                              hipStream_t stream) {
    const float* feats = (const float*)d_in[0];
    const float* intr  = (const float*)d_in[1];
    const float* extr  = (const float*)d_in[2];
    const float* convw = (const float*)d_in[3];
    const float* convb = (const float*)d_in[4];
    const float* gamma = (const float*)d_in[5];
    const float* beta  = (const float*)d_in[6];
    const float* mean  = (const float*)d_in[7];
    const float* var   = (const float*)d_in[8];

    char* ws = (char*)d_ws;
    float*          params = (float*)(ws + 0);              // 1152 B
    float*          sb     = (float*)(ws + 2048);           // 2 KB
    unsigned short* wbf    = (unsigned short*)(ws + 4096);  // 128 KB
    unsigned short* ft     = (unsigned short*)(ws + 135168);// 17.0 MB
    float* out = (float*)d_out;

    hipLaunchKernelGGL(prep_transpose_kernel, dim3(697), dim3(256), 0, stream,
                       feats, intr, extr, convw, convb, gamma, beta, mean, var,
                       params, sb, wbf, ft);
    hipLaunchKernelGGL(fused_kernel, dim3(625, 4), dim3(512), 0, stream,
                       ft, params, wbf, sb, out);
}

// Round 7
// 76.865 us; speedup vs baseline: 1.4203x; 1.0315x over previous
//
#include <hip/hip_runtime.h>
#include <hip/hip_bf16.h>

// BEVFormerLite fused: project BEV grid into 6 cameras, bilinear-sample,
// average valid cams, 1x1 conv + BN + ReLU.
// B=4 N=6 C=256 fH=29 fW=50, BEV 200x200 (P=40000). Output (4,256,200,200) f32.
//
// Round 7 = round 6 + two conflict/throughput fixes:
//  (a) phase B channel assignment chunk-interleaved (chunk = qv*8+sub) so the
//      Bt u16x8 stores hit bank-quad (p+s)%8 -> dense (was 8-way conflict,
//      3.2M conflict cycles measured in r5's profile).
//  (b) prep_transpose reads as float2 (pairs never cross the 50-wide row).
//  Structure otherwise r6: 512thr/8 waves, 64 pts, direct-L2 W in phase C,
//  launch_bounds(512,4) (r4 proved the 85-VGPR cap costs ~9us).

#define P_TOT  40000
#define FH     29
#define FW     50
#define NCAM   6

typedef short bf16x8 __attribute__((ext_vector_type(8)));
typedef float f32x4  __attribute__((ext_vector_type(4)));
typedef unsigned short u16x8 __attribute__((ext_vector_type(8)));

__device__ __forceinline__ float bf2f(unsigned short u) {
    union { unsigned int i; float f; } x; x.i = ((unsigned int)u) << 16; return x.f;
}
__device__ __forceinline__ unsigned short f2bf(float f) {
    union { float f; unsigned int i; } x; x.f = f;
    unsigned int i = x.i;
    return (unsigned short)((i + 0x7FFFu + ((i >> 16) & 1u)) >> 16);  // RNE
}

// ---------------- k0: transpose + W->bf16 + geometry + BN fold ----------------
__global__ __launch_bounds__(256) void prep_transpose_kernel(
        const float* __restrict__ feats, const float* __restrict__ K,
        const float* __restrict__ E, const float* __restrict__ convw,
        const float* __restrict__ convb, const float* __restrict__ gamma,
        const float* __restrict__ beta, const float* __restrict__ mean,
        const float* __restrict__ var, float* __restrict__ params,
        float* __restrict__ sb, unsigned short* __restrict__ wbf,
        unsigned short* __restrict__ ft) {
    __shared__ unsigned short tile[256][58];   // pad 50->58 (116B stride)
    int blk = blockIdx.x;
    int t   = threadIdx.x;
    if (blk < 256) {                           // W -> bf16 (65536 entries)
        int idx = blk * 256 + t;
        wbf[idx] = f2bf(convw[idx]);
    }
    if (blk == 696) {                          // geometry + BN fold
        int o = t;
        float rstd = rsqrtf(var[o] + 1e-5f);
        float s = gamma[o] * rstd;
        sb[o]       = s;
        sb[256 + o] = (convb[o] - mean[o]) * s + beta[o];
        if (o >= 24) return;
        const float* e = E + o * 16;
        const float* k = K + o * 9;
        float a00=e[0], a01=e[1], a02=e[2],  t0=e[3];
        float a10=e[4], a11=e[5], a12=e[6],  t1=e[7];
        float a20=e[8], a21=e[9], a22=e[10], t2=e[11];
        float c00 =  (a11*a22 - a12*a21);
        float c01 = -(a10*a22 - a12*a20);
        float c02 =  (a10*a21 - a11*a20);
        float det = a00*c00 + a01*c01 + a02*c02;
        float id = 1.0f / det;
        float i00 =  c00*id;
        float i01 = -(a01*a22 - a02*a21)*id;
        float i02 =  (a01*a12 - a02*a11)*id;
        float i10 =  c01*id;
        float i11 =  (a00*a22 - a02*a20)*id;
        float i12 = -(a00*a12 - a02*a10)*id;
        float i20 =  c02*id;
        float i21 = -(a00*a21 - a01*a20)*id;
        float i22 =  (a00*a11 - a01*a10)*id;
        float tp0 = -(i00*t0 + i01*t1 + i02*t2);
        float tp1 = -(i10*t0 + i11*t1 + i12*t2);
        float tp2 = -(i20*t0 + i21*t1 + i22*t2);
        float* q = params + o * 12;
        q[0] = k[0]*i00 + k[1]*i10 + k[2]*i20;
        q[1] = k[0]*i01 + k[1]*i11 + k[2]*i21;
        q[2] = k[0]*tp0 + k[1]*tp1 + k[2]*tp2;
        q[3] = k[3]*i00 + k[4]*i10 + k[5]*i20;
        q[4] = k[3]*i01 + k[4]*i11 + k[5]*i21;
        q[5] = k[3]*tp0 + k[4]*tp1 + k[5]*tp2;
        q[6] = k[6]*i00 + k[7]*i10 + k[8]*i20;
        q[7] = k[6]*i01 + k[7]*i11 + k[8]*i21;
        q[8] = k[6]*tp0 + k[7]*tp1 + k[8]*tp2;
        q[9]  = i20;
        q[10] = i21;
        q[11] = tp2;
        return;
    }
    // transpose one (bn,y) row: feats (bn,c,y,x) f32 -> ft (bn,y,x,c) bf16
    int bn = blk / FH, y = blk - bn * FH;
    const float* src = feats + (size_t)bn * 256 * FH * FW + y * FW;
    #pragma unroll
    for (int i = 0; i < 25; ++i) {             // float2 reads; pairs stay in-row (50 even)
        int flat = i * 512 + t * 2;
        int c = flat / 50;
        int x = flat - c * 50;
        float2 v = *(const float2*)(src + c * FH * FW + x);
        tile[c][x]     = f2bf(v.x);
        tile[c][x + 1] = f2bf(v.y);
    }
    __syncthreads();
    unsigned short* dst = ft + (size_t)blk * 50 * 256;
    #pragma unroll
    for (int i = 0; i < 25; ++i) {             // writes: fully coalesced u32
        int flat = i * 512 + t * 2;
        int x = flat >> 8;
        int c = flat & 255;
        unsigned int v = (unsigned int)tile[c][x] | ((unsigned int)tile[c + 1][x] << 16);
        *(unsigned int*)(dst + x * 256 + c) = v;
    }
}

// ---------------- k1: fused sample + GEMM + BN + ReLU ----------------
__global__ __launch_bounds__(512, 4) void fused_kernel(const unsigned short* __restrict__ ft,
                                                       const float* __restrict__ params,
                                                       const unsigned short* __restrict__ wbf,
                                                       const float* __restrict__ sb,
                                                       float* __restrict__ out) {
    __shared__ unsigned short Bt[64][264];        // bev tile [p][c], 528B rows
    __shared__ int           sbf[64][6];          // slot: base|okx|oky, -1 = invalid
    __shared__ unsigned int  swxy[64][6];         // wx,wy as u16 fixed-point
    __shared__ int           scnt[64];
    __shared__ float         sscale[64];
    __shared__ float         ssb[512];            // scale[256] + bias[256]

    int tid   = threadIdx.x;
    int pbase = blockIdx.x * 64;
    int b     = blockIdx.y;

    ssb[tid] = sb[tid];

    // ---- phase A: projection, one thread per (point, cam) ----
    if (tid < 384) {
        int pt  = tid / 6;
        int cam = tid - pt * 6;
        int p   = pbase + pt;
        float gx = -49.75f + 0.5f * (float)(p % 200);
        float gy = -49.75f + 0.5f * (float)(p / 200);
        const float* q = params + (b * NCAM + cam) * 12;
        float wh    = q[6] * gx + q[7]  * gy + q[8];
        float depth = q[9] * gx + q[10] * gy + q[11];
        float inv = 1.0f / (wh + 1e-6f);
        float u = (q[0] * gx + q[1] * gy + q[2]) * inv;
        float v = (q[3] * gx + q[4] * gy + q[5]) * inv;
        float un = u * (50.0f / 1600.0f) * (2.0f / 49.0f) - 1.0f;
        float vn = v * (29.0f / 928.0f)  * (2.0f / 28.0f) - 1.0f;
        int bf = -1; unsigned int wxy = 0;
        if (depth > 0.1f && un >= -1.0f && un <= 1.0f &&
                            vn >= -1.0f && vn <= 1.0f) {
            float xs = (un + 1.0f) * 0.5f * 49.0f;
            float ys = (vn + 1.0f) * 0.5f * 28.0f;
            float x0f = floorf(xs), y0f = floorf(ys);
            float wx = xs - x0f, wy = ys - y0f;
            int x0 = (int)x0f, y0 = (int)y0f;
            int okx = (x0 < FW - 1) ? 1 : 0;
            int oky = (y0 < FH - 1) ? 2 : 0;
            int base = (((b * NCAM + cam) * FH + y0) * FW + x0) * 256; // low 8 bits free
            bf  = base | okx | oky;
            wxy = (unsigned int)(wx * 65535.0f + 0.5f)
                | ((unsigned int)(wy * 65535.0f + 0.5f) << 16);
        }
        sbf[pt][cam]  = bf;
        swxy[pt][cam] = wxy;
    }
    __syncthreads();

    // ---- compact slots per point (cam order preserved) ----
    if (tid < 64) {
        int c = 0;
        #pragma unroll
        for (int cam = 0; cam < NCAM; ++cam) {
            int v = sbf[tid][cam];
            unsigned int w = swxy[tid][cam];
            if (v >= 0) { sbf[tid][c] = v; swxy[tid][c] = w; ++c; }
        }
        scnt[tid]   = c;
        sscale[tid] = 1.0f / ((float)c + 1e-6f);
    }
    __syncthreads();

    // ---- phase B: sample, 8 threads/point x 32 channels, chunk-interleaved ----
    // sub-thread s owns 16B chunks {s, s+8, s+16, s+24} of the 512B channel row
    // (channel offset sub*8 + qv*64). Bt store bank-quad = (p+s)%8 -> dense.
    {
        int pt = tid >> 3, sub = tid & 7;
        int chb = sub * 8;                       // base channel of chunk qv=0
        float acc[32];
        #pragma unroll
        for (int j = 0; j < 32; ++j) acc[j] = 0.0f;
        int n = scnt[pt];
        for (int s = 0; s < n; ++s) {
            int bf = sbf[pt][s];
            unsigned int wxy = swxy[pt][s];
            int base = bf & ~255;
            int okx = bf & 1, oky = bf & 2;
            float wx = (float)(wxy & 0xffffu) * (1.0f / 65535.0f);
            float wy = (float)(wxy >> 16)     * (1.0f / 65535.0f);
            float iwx = 1.0f - wx, iwy = 1.0f - wy;
            float w00 = iwx * iwy;
            float w01 = okx ? wx * iwy : 0.0f;
            float w10 = oky ? iwx * wy : 0.0f;
            float w11 = (okx && oky) ? wx * wy : 0.0f;
            const unsigned short* p00 = ft + base + chb;
            int o01 = okx ? 256 : 0;
            int o10 = oky ? FW * 256 : 0;
            #pragma unroll
            for (int qv = 0; qv < 4; ++qv) {
                u16x8 v0 = *(const u16x8*)(p00 + qv * 64);
                #pragma unroll
                for (int j = 0; j < 8; ++j) acc[qv * 8 + j] += w00 * bf2f(v0[j]);
            }
            #pragma unroll
            for (int qv = 0; qv < 4; ++qv) {
                u16x8 v1 = *(const u16x8*)(p00 + o01 + qv * 64);
                #pragma unroll
                for (int j = 0; j < 8; ++j) acc[qv * 8 + j] += w01 * bf2f(v1[j]);
            }
            #pragma unroll
            for (int qv = 0; qv < 4; ++qv) {
                u16x8 v2 = *(const u16x8*)(p00 + o10 + qv * 64);
                #pragma unroll
                for (int j = 0; j < 8; ++j) acc[qv * 8 + j] += w10 * bf2f(v2[j]);
            }
            #pragma unroll
            for (int qv = 0; qv < 4; ++qv) {
                u16x8 v3 = *(const u16x8*)(p00 + o10 + o01 + qv * 64);
                #pragma unroll
                for (int j = 0; j < 8; ++j) acc[qv * 8 + j] += w11 * bf2f(v3[j]);
            }
        }
        float sc = sscale[pt];
        #pragma unroll
        for (int qv = 0; qv < 4; ++qv) {
            u16x8 ov;
            #pragma unroll
            for (int j = 0; j < 8; ++j) ov[j] = f2bf(acc[qv * 8 + j] * sc);
            *(u16x8*)&Bt[pt][chb + qv * 64] = ov;
        }
    }
    __syncthreads();

    // ---- phase C: GEMM, 8 waves x (32o x 64p), K=256, A direct from L2, no barriers ----
    int lane = tid & 63, wv = tid >> 6;
    f32x4 acc2[2][4];
    #pragma unroll
    for (int f = 0; f < 2; ++f)
        #pragma unroll
        for (int nf = 0; nf < 4; ++nf) acc2[f][nf] = (f32x4){0.f, 0.f, 0.f, 0.f};
    int arow = wv * 32 + (lane & 15);
    int kq   = (lane >> 4) * 8;
    const unsigned short* wptr = wbf + arow * 256 + kq;   // W is L2-resident (128KB)
    #pragma unroll
    for (int kt = 0; kt < 8; ++kt) {
        bf16x8 a0 = *(const bf16x8*)(wptr + kt * 32);
        bf16x8 a1 = *(const bf16x8*)(wptr + 16 * 256 + kt * 32);
        #pragma unroll
        for (int nf = 0; nf < 4; ++nf) {
            bf16x8 bb = *(const bf16x8*)&Bt[nf * 16 + (lane & 15)][kt * 32 + kq];
            acc2[0][nf] = __builtin_amdgcn_mfma_f32_16x16x32_bf16(a0, bb, acc2[0][nf], 0, 0, 0);
            acc2[1][nf] = __builtin_amdgcn_mfma_f32_16x16x32_bf16(a1, bb, acc2[1][nf], 0, 0, 0);
        }
    }
    // ---- epilogue: BN + ReLU + store ----
    #pragma unroll
    for (int f = 0; f < 2; ++f) {
        #pragma unroll
        for (int nf = 0; nf < 4; ++nf) {
            #pragma unroll
            for (int r = 0; r < 4; ++r) {
                int o = wv * 32 + f * 16 + (lane >> 4) * 4 + r;
                float y = acc2[f][nf][r] * ssb[o] + ssb[256 + o];
                out[((size_t)(b * 256 + o)) * P_TOT + pbase + nf * 16 + (lane & 15)]
                    = fmaxf(y, 0.0f);
            }
        }
    }
}

extern "C" void kernel_launch(void* const* d_in, const int* in_sizes, int n_in,
                              void* d_out, int out_size, void* d_ws, size_t ws_size,
                              hipStream_t stream) {
    const float* feats = (const float*)d_in[0];
    const float* intr  = (const float*)d_in[1];
    const float* extr  = (const float*)d_in[2];
    const float* convw = (const float*)d_in[3];
    const float* convb = (const float*)d_in[4];
    const float* gamma = (const float*)d_in[5];
    const float* beta  = (const float*)d_in[6];
    const float* mean  = (const float*)d_in[7];
    const float* var   = (const float*)d_in[8];

    char* ws = (char*)d_ws;
    float*          params = (float*)(ws + 0);              // 1152 B
    float*          sb     = (float*)(ws + 2048);           // 2 KB
    unsigned short* wbf    = (unsigned short*)(ws + 4096);  // 128 KB
    unsigned short* ft     = (unsigned short*)(ws + 135168);// 17.0 MB
    float* out = (float*)d_out;

    hipLaunchKernelGGL(prep_transpose_kernel, dim3(697), dim3(256), 0, stream,
                       feats, intr, extr, convw, convb, gamma, beta, mean, var,
                       params, sb, wbf, ft);
    hipLaunchKernelGGL(fused_kernel, dim3(625, 4), dim3(512), 0, stream,
                       ft, params, wbf, sb, out);
}